// Round 13
// baseline (161.180 us; speedup 1.0000x reference)
//
#include <hip/hip_runtime.h>
#include <math.h>

#define HI 256
#define WI 256
#define NIMG 128          // B*S
#define NP 68             // landmarks
#define NT 16             // 4x4 tiles of 16x16 outputs per 64x64 heatmap
#define NPAIR 120         // B*(S-1)
#define K_LK 289          // 17x17 window
#define NCONVB (NT * NIMG)   // 2048 conv blocks
#define NGRAYB 1024          // gray blocks appended after conv blocks
#define NTASK (2 * NPAIR * NP)   // 16320 LK tasks

typedef float f4v __attribute__((ext_vector_type(4)));
typedef float f2v __attribute__((ext_vector_type(2)));
typedef f4v __attribute__((aligned(4))) uf4;
typedef f2v __attribute__((aligned(4))) uf2;

typedef short bfv8 __attribute__((ext_vector_type(8)));   // 8 bf16 (MFMA frag)
typedef bfv8 __attribute__((aligned(8))) ubfv8;           // 8B-aligned LDS view

#define WBF_ELEMS (3 * 8 * 80 * 8)   // bf16 weight image [c][ky0..7][f0..79][kx0..7]

__device__ __forceinline__ short f2bf(float x) {
    unsigned u = __builtin_bit_cast(unsigned, x);
    u += 0x7fffu + ((u >> 16) & 1u);          // round-to-nearest-even
    return (short)(u >> 16);
}
__device__ __forceinline__ unsigned pk2(float lo, float hi) {
    return (unsigned)(unsigned short)f2bf(lo) | ((unsigned)(unsigned short)f2bf(hi) << 16);
}

// ---- DPP wave-64 sum; lane 63 holds the total (6 VALU ops, no LDS round-trip)
#define DPPA(ctrl, rm)                                                          \
    {                                                                           \
        int m_ = __builtin_amdgcn_update_dpp(0, __builtin_bit_cast(int, x),     \
                                             ctrl, rm, 0xf, true);              \
        x += __builtin_bit_cast(float, m_);                                     \
    }
__device__ __forceinline__ float wave_sum64(float x) {
    DPPA(0x111, 0xf)   // row_shr:1
    DPPA(0x112, 0xf)   // row_shr:2
    DPPA(0x114, 0xf)   // row_shr:4
    DPPA(0x118, 0xf)   // row_shr:8
    DPPA(0x142, 0xa)   // row_bcast:15 -> rows 1,3
    DPPA(0x143, 0xc)   // row_bcast:31 -> rows 2,3
    return x;          // lane 63 = total
}
__device__ __forceinline__ float rl63(float x) {
    return __builtin_bit_cast(float,
        __builtin_amdgcn_readlane(__builtin_bit_cast(int, x), 63));
}

// ---------------------------------------------------------------------------
// Kernel 0: weight prep (ONCE) -> bf16 [c][ky(8)][p(80)][kx(8)], pads zero.
// ---------------------------------------------------------------------------
__global__ __launch_bounds__(256) void k_wprep(const float* __restrict__ dw,
                                               short* __restrict__ wbf) {
    for (int k = threadIdx.x; k < WBF_ELEMS / 2; k += 256) ((int*)wbf)[k] = 0;
    __syncthreads();
    for (int idx = threadIdx.x; idx < NP * 147; idx += 256) {
        int p = idx / 147;
        int rem = idx - p * 147;
        int ck = rem / 7;            // c*7+ky
        int kx = rem - ck * 7;
        int c = ck / 7;
        int ky = ck - c * 7;
        wbf[((c * 8 + ky) * 80 + p) * 8 + kx] = f2bf(dw[idx]);
    }
}

// ---------------------------------------------------------------------------
// Kernel 1 (fused): blocks [0, NCONVB): conv 7x7/s4 MFMA + softmax stats
//                   blocks [NCONVB, NCONVB+NGRAYB): gray = channel mean
// ---------------------------------------------------------------------------
#define IN_RS 72                     // LDS input row stride (shorts), 144B
__global__ __launch_bounds__(256, 3) void k_convgray(const float* __restrict__ in,
                                                     const short* __restrict__ wbf,
                                                     float* __restrict__ stats,
                                                     float* __restrict__ gray) {
    const int bid = blockIdx.x;
    if (bid >= NCONVB) {
        // ---------------- gray part ----------------
        const int QT = HI * WI / 4;
        const int total = NIMG * QT;
        const float4* in4 = (const float4*)in;
        float4* g4 = (float4*)gray;
        const float kk = 1.0f / 3.0f;
        for (int idx = (bid - NCONVB) * 256 + threadIdx.x; idx < total;
             idx += NGRAYB * 256) {
            int img = idx / QT;
            int off = idx - img * QT;
            const float4* base = in4 + (size_t)img * 3 * QT + off;
            float4 a = base[0];
            float4 b = base[QT];
            float4 c = base[2 * QT];
            float4 o;
            o.x = (a.x + b.x + c.x) * kk;
            o.y = (a.y + b.y + c.y) * kk;
            o.z = (a.z + b.z + c.z) * kk;
            o.w = (a.w + b.w + c.w) * kk;
            g4[idx] = o;
        }
        return;
    }
    // ---------------- conv part ----------------
    const int tile = bid & 15;
    const int n = bid >> 4;
    const int ty0 = (tile >> 2) * 16;
    const int tx0 = (tile & 3) * 16;
    const int tid = threadIdx.x;
    const int w = __builtin_amdgcn_readfirstlane(tid >> 6);   // wave: rows 4w..4w+3
    const int lane = tid & 63;
    const int lx = lane & 15;        // pixel x (A) / filter (B)
    const int lg = lane >> 4;        // k-group

    __shared__ short in_lds[3 * 68 * IN_RS];    // 29376 B bf16, col idx = C-(4tx0-1)
    __shared__ float part_m[4][80];
    __shared__ float Mf[80];
    __shared__ float part_s[4][80], part_sx[4][80], part_sy[4][80];

    const float* img = in + (size_t)n * 3 * HI * WI;

    // ---- stage input patch: thread t = row t of 204 (3ch x 68 rows) ----
    if (tid < 204) {
        int c = tid / 68;
        int r = tid - c * 68;
        int R = 4 * ty0 - 1 + r;
        unsigned wb[36];
        if ((unsigned)R < HI) {
            const float* src = img + (size_t)c * HI * WI + (size_t)R * WI + (4 * tx0 - 1);
            float f[70];
            f[0] = (tx0 > 0) ? src[0] : 0.0f;       // col 4tx0-1 (OOB only tx0=0)
            const float* s2 = src + 1;              // col 4tx0, 16B-aligned
#pragma unroll
            for (int q = 0; q < 16; ++q) {
                f4v v = *(const f4v*)(s2 + 4 * q);
                f[1 + 4 * q] = v.x; f[2 + 4 * q] = v.y;
                f[3 + 4 * q] = v.z; f[4 + 4 * q] = v.w;
            }
            if (tx0 < 48) {                         // cols 4tx0+64..67 in-range
                f4v v = *(const f4v*)(s2 + 64);
                f[65] = v.x; f[66] = v.y; f[67] = v.z; f[68] = v.w;
            } else {
                f[65] = 0.0f; f[66] = 0.0f; f[67] = 0.0f; f[68] = 0.0f;
            }
            f[69] = 0.0f;
#pragma unroll
            for (int j = 0; j < 35; ++j) wb[j] = pk2(f[2 * j], f[2 * j + 1]);
            wb[35] = 0;
        } else {
#pragma unroll
            for (int j = 0; j < 36; ++j) wb[j] = 0;
        }
        uint4* dst = (uint4*)&in_lds[(c * 68 + r) * IN_RS];   // 144B row, 16B-aligned
#pragma unroll
        for (int q = 0; q < 9; ++q) {
            uint4 u;
            u.x = wb[4 * q]; u.y = wb[4 * q + 1]; u.z = wb[4 * q + 2]; u.w = wb[4 * q + 3];
            dst[q] = u;
        }
    }
    __syncthreads();

    // ---- main MFMA loop ----
    f4v acc[4][5];
#pragma unroll
    for (int a = 0; a < 4; ++a)
#pragma unroll
        for (int b = 0; b < 5; ++b) acc[a][b] = (f4v)0.0f;

#pragma unroll
    for (int c = 0; c < 3; ++c) {
#pragma unroll
        for (int kyg = 0; kyg < 2; ++kyg) {
            const int ky = kyg * 4 + lg;                     // 0..7 (7 = pad plane)
            const bfv8* wp = (const bfv8*)(wbf + ((c * 8 + ky) * 80 + lx) * 8);
            bfv8 B0 = wp[0];
            bfv8 B1 = wp[16];
            bfv8 B2 = wp[32];
            bfv8 B3 = wp[48];
            bfv8 B4 = wp[64];
            const short* ibase = &in_lds[c * (68 * IN_RS) + ky * IN_RS + 4 * lx];
#pragma unroll
            for (int mt = 0; mt < 4; ++mt) {
                bfv8 A = *(const ubfv8*)(ibase + (16 * w + 4 * mt) * IN_RS);
                acc[mt][0] = __builtin_amdgcn_mfma_f32_16x16x32_bf16(A, B0, acc[mt][0], 0, 0, 0);
                acc[mt][1] = __builtin_amdgcn_mfma_f32_16x16x32_bf16(A, B1, acc[mt][1], 0, 0, 0);
                acc[mt][2] = __builtin_amdgcn_mfma_f32_16x16x32_bf16(A, B2, acc[mt][2], 0, 0, 0);
                acc[mt][3] = __builtin_amdgcn_mfma_f32_16x16x32_bf16(A, B3, acc[mt][3], 0, 0, 0);
                acc[mt][4] = __builtin_amdgcn_mfma_f32_16x16x32_bf16(A, B4, acc[mt][4], 0, 0, 0);
            }
        }
    }

    // ---- epilogue: softmax stats. lane holds px x=(lg*4+q), filter lx+16nt ----
#pragma unroll
    for (int nt = 0; nt < 5; ++nt) {
        float m = -3.4e38f;
#pragma unroll
        for (int mt = 0; mt < 4; ++mt)
#pragma unroll
            for (int q = 0; q < 4; ++q) m = fmaxf(m, acc[mt][nt][q]);
        m = fmaxf(m, __shfl_xor(m, 16, 64));
        m = fmaxf(m, __shfl_xor(m, 32, 64));
        if (lg == 0) part_m[w][nt * 16 + lx] = m;
    }
    __syncthreads();
    if (tid < 80)
        Mf[tid] = fmaxf(fmaxf(part_m[0][tid], part_m[1][tid]),
                        fmaxf(part_m[2][tid], part_m[3][tid]));
    __syncthreads();

#pragma unroll
    for (int nt = 0; nt < 5; ++nt) {
        float M = Mf[nt * 16 + lx];
        float s = 0.0f, sx = 0.0f, sy = 0.0f;
#pragma unroll
        for (int mt = 0; mt < 4; ++mt) {
            float yv = (float)(ty0 + 4 * w + mt);
#pragma unroll
            for (int q = 0; q < 4; ++q) {
                float e = __expf(acc[mt][nt][q] - M);
                s += e;
                sx += e * (float)(tx0 + lg * 4 + q);
                sy += e * yv;
            }
        }
        s += __shfl_xor(s, 16, 64);  s += __shfl_xor(s, 32, 64);
        sx += __shfl_xor(sx, 16, 64); sx += __shfl_xor(sx, 32, 64);
        sy += __shfl_xor(sy, 16, 64); sy += __shfl_xor(sy, 32, 64);
        if (lg == 0) {
            part_s[w][nt * 16 + lx] = s;
            part_sx[w][nt * 16 + lx] = sx;
            part_sy[w][nt * 16 + lx] = sy;
        }
    }
    __syncthreads();
    if (tid < NP) {
        float S = part_s[0][tid] + part_s[1][tid] + part_s[2][tid] + part_s[3][tid];
        float SX = part_sx[0][tid] + part_sx[1][tid] + part_sx[2][tid] + part_sx[3][tid];
        float SY = part_sy[0][tid] + part_sy[1][tid] + part_sy[2][tid] + part_sy[3][tid];
        float4* o = (float4*)(stats + (((size_t)n * NP + tid) * NT + tile) * 4);
        *o = make_float4(Mf[tid], S, SX, SY);
    }
}

// ---------------------------------------------------------------------------
// Kernel 2: iterative Lucas-Kanade + per-point centroid.
// R12 result: VGPR landed exactly 64 but runtime stayed at the 4-wave/SIMD
// tier (timing arithmetic: 16 blk/CU / 4 concurrent x 24us = 96us observed).
// Hypothesis: 8-wave tier needs VGPR STRICTLY below 64 (granule 8 -> 56).
// R13: per-sample sched_barrier(0) caps in-flight loads at one sample's
// worth (~2-4 regs transient vs ~10-20 hoisted) -> target VGPR <= 56.
// No launch_bounds coercion (R8/R9: forced caps spill catastrophically).
// Also: bxv/byv as 2-way accumulator trees (shorter dep chain, free).
// ---------------------------------------------------------------------------
__device__ __forceinline__ float bil(const float* __restrict__ img, float x, float y) {
    float x0f = floorf(x), y0f = floorf(y);
    float wx = x - x0f, wy = y - y0f;
    int x0 = (int)x0f, y0 = (int)y0f;
    int x0i = min(max(x0, 0), WI - 1);
    int x1i = min(x0i + 1, WI - 1);
    int y0i = min(max(y0, 0), HI - 1);
    int y1i = min(y0i + 1, HI - 1);
    float v00 = img[y0i * WI + x0i];
    float v01 = img[y0i * WI + x1i];
    float v10 = img[y1i * WI + x0i];
    float v11 = img[y1i * WI + x1i];
    return v00 * (1.0f - wx) * (1.0f - wy) + v01 * wx * (1.0f - wy)
         + v10 * (1.0f - wx) * wy + v11 * wx * wy;
}

// rowoff for sample 4 (k = 256+lane), recomputed per use (saves a VGPR):
// lane<16: dy=15,dx=lane+1 -> 3841+lane ; lane 16..32: dy=16,dx=lane-16 ->
// 4080+lane ; lane>=33: masked slot -> 0.
__device__ __forceinline__ int ro4_of(int lane) {
    int v = (lane < 16) ? (3841 + lane) : (4080 + lane);
    return (lane < 33) ? v : 0;
}

__device__ __forceinline__ void centroid_of(const float* __restrict__ stats,
                                            int n, int j, int lane,
                                            float& cx, float& cy) {
    const float4* st = (const float4*)(stats + (((size_t)n * NP + j) * NT) * 4);
    float4 v = st[lane & 15];
    float M = v.x, S = v.y, SX = v.z, SY = v.w;
#pragma unroll
    for (int d = 1; d < 16; d <<= 1) {
        float Mo = __shfl_xor(M, d, 64);
        float So = __shfl_xor(S, d, 64);
        float Xo = __shfl_xor(SX, d, 64);
        float Yo = __shfl_xor(SY, d, 64);
        float M2 = fmaxf(M, Mo);
        float e0 = __expf(M - M2);
        float e1 = __expf(Mo - M2);
        S = S * e0 + So * e1;
        SX = SX * e0 + Xo * e1;
        SY = SY * e0 + Yo * e1;
        M = M2;
    }
    cx = SX / S * 4.0f;     // identical in every 16-lane group -> wave-uniform
    cy = SY / S * 4.0f;
}

__device__ void lk_track(const float* __restrict__ I, const float* __restrict__ J,
                         int lane, float x, float y, float& ox_, float& oy_) {
    int rowoff[4];
    float Gx[5], Gy[5];
#pragma unroll
    for (int i = 0; i < 4; ++i) {
        int k = lane + 64 * i;
        rowoff[i] = (k / 17) * WI + k % 17;
    }

    float ixf = floorf(x), iyf = floorf(y);
    float wx = x - ixf, wy = y - iyf;
    float w00 = (1.0f - wx) * (1.0f - wy);
    float w01 = wx * (1.0f - wy);
    float w10 = (1.0f - wx) * wy;
    float w11 = wx * wy;

    float a11 = 0.0f, a12 = 0.0f, a22 = 0.0f, gxt = 0.0f, gyt = 0.0f;
    int fastI = (ixf >= 9.0f) && (ixf <= 245.0f) && (iyf >= 9.0f) && (iyf <= 245.0f);
    fastI = __builtin_amdgcn_readfirstlane(fastI);
    if (fastI) {
        int ibase = __builtin_amdgcn_readfirstlane(((int)iyf - 8) * WI + (int)ixf - 8);
        const float* Ib = I + ibase;                 // SGPR base; rowoff = voffset
#pragma unroll
        for (int i = 0; i < 5; ++i) {
            const float* p = Ib + ((i < 4) ? rowoff[i] : ro4_of(lane));
            f4v r0 = *(const uf4*)(p - 1);           // imm -4
            f4v r1 = *(const uf4*)(p + WI - 1);      // imm +1020
            f2v rm = *(const uf2*)(p - WI);          // imm -1024
            f2v r2 = *(const uf2*)(p + 2 * WI);      // imm +2048
            float t   = w00 * r0.y + w01 * r0.z + w10 * r1.y + w11 * r1.z;
            float tx1 = w00 * r0.z + w01 * r0.w + w10 * r1.z + w11 * r1.w;
            float txm = w00 * r0.x + w01 * r0.y + w10 * r1.x + w11 * r1.y;
            float typ = w00 * r1.y + w01 * r1.z + w10 * r2.x + w11 * r2.y;
            float tym = w00 * rm.x + w01 * rm.y + w10 * r0.y + w11 * r0.z;
            float gx = 0.5f * (tx1 - txm);
            float gy = 0.5f * (typ - tym);
            if (i == 4 && lane >= 33) { t = 0.0f; gx = 0.0f; gy = 0.0f; }
            Gx[i] = gx; Gy[i] = gy;
            gxt = fmaf(gx, t, gxt); gyt = fmaf(gy, t, gyt);
            a11 = fmaf(gx, gx, a11); a12 = fmaf(gx, gy, a12); a22 = fmaf(gy, gy, a22);
            if (i < 4) __builtin_amdgcn_sched_barrier(0);   // 1 sample's loads in flight
        }
    } else {
#pragma unroll
        for (int i = 0; i < 5; ++i) {
            int k = lane + 64 * i;
            bool v_ = (k < K_LK);
            int kk = v_ ? k : 0;
            float fx = x + (float)(kk % 17 - 8);
            float fy = y + (float)(kk / 17 - 8);
            float t = bil(I, fx, fy);
            float gx = (bil(I, fx + 1.0f, fy) - bil(I, fx - 1.0f, fy)) * 0.5f;
            float gy = (bil(I, fx, fy + 1.0f) - bil(I, fx, fy - 1.0f)) * 0.5f;
            if (!v_) { t = 0.0f; gx = 0.0f; gy = 0.0f; }
            Gx[i] = gx; Gy[i] = gy;
            gxt = fmaf(gx, t, gxt); gyt = fmaf(gy, t, gyt);
            a11 = fmaf(gx, gx, a11); a12 = fmaf(gx, gy, a12); a22 = fmaf(gy, gy, a22);
            if (i < 4) __builtin_amdgcn_sched_barrier(0);
        }
    }
    a11 = rl63(wave_sum64(a11)) + 1e-6f;
    a12 = rl63(wave_sum64(a12));
    a22 = rl63(wave_sum64(a22)) + 1e-6f;
    float S_GxT = rl63(wave_sum64(gxt));
    float S_GyT = rl63(wave_sum64(gyt));
    float det = a11 * a22 - a12 * a12;
    float i11 = a22 / det, i12 = -a12 / det, i22 = a11 / det;

    float px = x, py = y;
#pragma unroll 1
    for (int s = 0; s < 10; ++s) {
        float bxv0 = 0.0f, byv0 = 0.0f, bxv1 = 0.0f, byv1 = 0.0f;
        float jxf = floorf(px), jyf = floorf(py);
        float vx = px - jxf, vy = py - jyf;
        float u00 = (1.0f - vx) * (1.0f - vy);
        float u01 = vx * (1.0f - vy);
        float u10 = (1.0f - vx) * vy;
        float u11 = vx * vy;
        int fastJ = (jxf >= 8.0f) && (jxf <= 246.0f) && (jyf >= 8.0f) && (jyf <= 246.0f);
        fastJ = __builtin_amdgcn_readfirstlane(fastJ);
        if (fastJ) {
            int jbase = __builtin_amdgcn_readfirstlane(((int)jyf - 8) * WI + (int)jxf - 8);
            const float* Jb = J + jbase;             // SGPR base; rowoff = voffset
#pragma unroll
            for (int i = 0; i < 5; ++i) {
                const float* p = Jb + ((i < 4) ? rowoff[i] : ro4_of(lane));
                f2v q0 = *(const uf2*)(p);
                f2v q1 = *(const uf2*)(p + WI);      // imm +1024
                float v = u00 * q0.x + u01 * q0.y + u10 * q1.x + u11 * q1.y;
                if (i & 1) { bxv1 = fmaf(Gx[i], v, bxv1); byv1 = fmaf(Gy[i], v, byv1); }
                else       { bxv0 = fmaf(Gx[i], v, bxv0); byv0 = fmaf(Gy[i], v, byv0); }
                if (i < 4) __builtin_amdgcn_sched_barrier(0);   // 1 sample in flight
            }
        } else {
#pragma unroll
            for (int i = 0; i < 5; ++i) {
                int k = lane + 64 * i;
                int kk = (k < K_LK) ? k : 0;
                float v = bil(J, px + (float)(kk % 17 - 8), py + (float)(kk / 17 - 8));
                if (i & 1) { bxv1 = fmaf(Gx[i], v, bxv1); byv1 = fmaf(Gy[i], v, byv1); }
                else       { bxv0 = fmaf(Gx[i], v, bxv0); byv0 = fmaf(Gy[i], v, byv0); }
                if (i < 4) __builtin_amdgcn_sched_barrier(0);
            }
        }
        float bxs = S_GxT - rl63(wave_sum64(bxv0 + bxv1));
        float bys = S_GyT - rl63(wave_sum64(byv0 + byv1));
        px = fmaf(i11, bxs, fmaf(i12, bys, px));
        py = fmaf(i12, bxs, fmaf(i22, bys, py));
    }
    ox_ = px;
    oy_ = py;
}

__global__ __launch_bounds__(256) void k_lk(const float* __restrict__ gray,
                                            const float* __restrict__ stats,
                                            float* __restrict__ locs,
                                            float* __restrict__ out_next,
                                            float* __restrict__ out_fb,
                                            float* __restrict__ out_back) {
    int wid = blockIdx.x * 4 + (threadIdx.x >> 6);   // 4 independent tasks/block
    int lane = threadIdx.x & 63;
    int variant = wid / (NPAIR * NP);
    int r = wid - variant * (NPAIR * NP);
    int pr = r / NP;
    int j = r - pr * NP;
    int b = pr / 15;
    int t = pr - b * 15;
    int n0 = b * 16 + t;
    const float* I = gray + (size_t)n0 * HI * WI;
    const float* J = gray + (size_t)(n0 + 1) * HI * WI;
    int o = (pr * NP + j) * 2;
    if (variant == 0) {
        float x, y;
        centroid_of(stats, n0, j, lane, x, y);
        if (lane == 0) { locs[(n0 * NP + j) * 2] = x; locs[(n0 * NP + j) * 2 + 1] = y; }
        float nx, ny;
        lk_track(I, J, lane, x, y, nx, ny);
        if (lane == 0) { out_next[o] = nx; out_next[o + 1] = ny; }
        float fx, fy;
        lk_track(J, I, lane, nx, ny, fx, fy);
        if (lane == 0) { out_fb[o] = fx; out_fb[o + 1] = fy; }
    } else {
        float x, y;
        centroid_of(stats, n0 + 1, j, lane, x, y);
        if (lane == 0) {
            locs[((n0 + 1) * NP + j) * 2] = x;
            locs[((n0 + 1) * NP + j) * 2 + 1] = y;
        }
        float bx, by;
        lk_track(J, I, lane, x, y, bx, by);
        if (lane == 0) { out_back[o] = bx; out_back[o + 1] = by; }
    }
}

// ---------------------------------------------------------------------------
extern "C" void kernel_launch(void* const* d_in, const int* in_sizes, int n_in,
                              void* d_out, int out_size, void* d_ws, size_t ws_size,
                              hipStream_t stream) {
    const float* inputs = (const float*)d_in[0];
    const float* det_w  = (const float*)d_in[1];
    // det_b (d_in[2]) is softmax-shift-invariant -> unused
    float* out = (float*)d_out;

    float* gray  = (float*)d_ws;                                       // 32 MiB
    float* stats = (float*)((char*)d_ws + (size_t)NIMG * HI * WI * 4); // 2.2 MiB
    short* wbf   = (short*)((char*)d_ws + (size_t)NIMG * HI * WI * 4
                            + (size_t)NIMG * NP * NT * 4 * 4);         // 30 KiB

    float* locs   = out;                    // [8,16,68,2]
    float* next_p = out + 17408;
    float* fb_p   = out + 33728;
    float* back_p = out + 50048;

    hipLaunchKernelGGL(k_wprep, dim3(1), dim3(256), 0, stream, det_w, wbf);
    hipLaunchKernelGGL(k_convgray, dim3(NCONVB + NGRAYB), dim3(256), 0, stream,
                       inputs, wbf, stats, gray);
    hipLaunchKernelGGL(k_lk, dim3(NTASK / 4), dim3(256), 0, stream,
                       gray, stats, locs, next_p, fb_p, back_p);
}

// Round 14
// 154.989 us; speedup vs baseline: 1.0399x; 1.0399x over previous
//
#include <hip/hip_runtime.h>
#include <math.h>

#define HI 256
#define WI 256
#define NIMG 128          // B*S
#define NP 68             // landmarks
#define NT 16             // 4x4 tiles of 16x16 outputs per 64x64 heatmap
#define NPAIR 120         // B*(S-1)
#define K_LK 289          // 17x17 window
#define NCONVB (NT * NIMG)   // 2048 conv blocks
#define NGRAYB 1024          // gray blocks appended after conv blocks
#define NTASK (2 * NPAIR * NP)   // 16320 LK tasks

typedef float f4v __attribute__((ext_vector_type(4)));
typedef float f2v __attribute__((ext_vector_type(2)));
typedef f4v __attribute__((aligned(4))) uf4;
typedef f2v __attribute__((aligned(4))) uf2;

typedef short bfv8 __attribute__((ext_vector_type(8)));   // 8 bf16 (MFMA frag)
typedef bfv8 __attribute__((aligned(8))) ubfv8;           // 8B-aligned LDS view

#define WBF_ELEMS (3 * 8 * 80 * 8)   // bf16 weight image [c][ky0..7][f0..79][kx0..7]

__device__ __forceinline__ short f2bf(float x) {
    unsigned u = __builtin_bit_cast(unsigned, x);
    u += 0x7fffu + ((u >> 16) & 1u);          // round-to-nearest-even
    return (short)(u >> 16);
}
__device__ __forceinline__ unsigned pk2(float lo, float hi) {
    return (unsigned)(unsigned short)f2bf(lo) | ((unsigned)(unsigned short)f2bf(hi) << 16);
}

// ---- DPP wave-64 sum; lane 63 holds the total (6 VALU ops, no LDS round-trip)
#define DPPA(ctrl, rm)                                                          \
    {                                                                           \
        int m_ = __builtin_amdgcn_update_dpp(0, __builtin_bit_cast(int, x),     \
                                             ctrl, rm, 0xf, true);              \
        x += __builtin_bit_cast(float, m_);                                     \
    }
__device__ __forceinline__ float wave_sum64(float x) {
    DPPA(0x111, 0xf)   // row_shr:1
    DPPA(0x112, 0xf)   // row_shr:2
    DPPA(0x114, 0xf)   // row_shr:4
    DPPA(0x118, 0xf)   // row_shr:8
    DPPA(0x142, 0xa)   // row_bcast:15 -> rows 1,3
    DPPA(0x143, 0xc)   // row_bcast:31 -> rows 2,3
    return x;          // lane 63 = total
}
__device__ __forceinline__ float rl63(float x) {
    return __builtin_bit_cast(float,
        __builtin_amdgcn_readlane(__builtin_bit_cast(int, x), 63));
}

// ---------------------------------------------------------------------------
// Kernel 0: weight prep -> bf16 [c][ky(8)][p(80)][kx(8)], pads zero.
// Grid 16; each int (2 shorts) computed directly (pad or data) -> no
// zero-pass/write race across blocks.
// ---------------------------------------------------------------------------
__global__ __launch_bounds__(256) void k_wprep(const float* __restrict__ dw,
                                               short* __restrict__ wbf) {
    for (int ii = blockIdx.x * 256 + threadIdx.x; ii < WBF_ELEMS / 2;
         ii += 16 * 256) {
        int s0 = 2 * ii;                 // short index, kx = s0 & 7 (even)
        int kx = s0 & 7;
        int rest = s0 >> 3;              // (c*8+ky)*80 + p
        int p = rest % 80;
        int cky = rest / 80;             // c*8+ky
        int c = cky >> 3;
        int ky = cky & 7;
        unsigned lo = 0, hi = 0;
        if (ky < 7 && p < NP) {
            const float* wp = dw + p * 147 + (c * 7 + ky) * 7;
            lo = (unsigned short)f2bf(wp[kx]);             // kx <= 6 here (kx even)
            if (kx + 1 < 7) hi = (unsigned short)f2bf(wp[kx + 1]);
        }
        ((int*)wbf)[ii] = (int)(lo | (hi << 16));
    }
}

// ---------------------------------------------------------------------------
// Kernel 1 (fused): blocks [0, NCONVB): conv 7x7/s4 MFMA + softmax stats
//                   blocks [NCONVB, NCONVB+NGRAYB): gray = channel mean
// R14: staging coalesced. Old scheme (1 thread = 1 row, 17 dwordx4 down a
// 1KB-strided column of rows) gave 64 cache lines PER INSTRUCTION. New:
// pass 1 puts 16 lanes side-by-side on the same row (256B contiguous),
// writing the SAME shifted LDS layout (x = C-4tx0+1) via b16/b32/b16 stores;
// pass 2 (1 thread/row) fills margin cols x=0,65..67. MFMA loop unchanged.
// ---------------------------------------------------------------------------
#define IN_RS 72                     // LDS input row stride (shorts), 144B
__global__ __launch_bounds__(256, 3) void k_convgray(const float* __restrict__ in,
                                                     const short* __restrict__ wbf,
                                                     float* __restrict__ stats,
                                                     float* __restrict__ gray) {
    const int bid = blockIdx.x;
    if (bid >= NCONVB) {
        // ---------------- gray part ----------------
        const int QT = HI * WI / 4;
        const int total = NIMG * QT;
        const float4* in4 = (const float4*)in;
        float4* g4 = (float4*)gray;
        const float kk = 1.0f / 3.0f;
        for (int idx = (bid - NCONVB) * 256 + threadIdx.x; idx < total;
             idx += NGRAYB * 256) {
            int img = idx / QT;
            int off = idx - img * QT;
            const float4* base = in4 + (size_t)img * 3 * QT + off;
            float4 a = base[0];
            float4 b = base[QT];
            float4 c = base[2 * QT];
            float4 o;
            o.x = (a.x + b.x + c.x) * kk;
            o.y = (a.y + b.y + c.y) * kk;
            o.z = (a.z + b.z + c.z) * kk;
            o.w = (a.w + b.w + c.w) * kk;
            g4[idx] = o;
        }
        return;
    }
    // ---------------- conv part ----------------
    const int tile = bid & 15;
    const int n = bid >> 4;
    const int ty0 = (tile >> 2) * 16;
    const int tx0 = (tile & 3) * 16;
    const int tid = threadIdx.x;
    const int w = __builtin_amdgcn_readfirstlane(tid >> 6);   // wave: rows 4w..4w+3
    const int lane = tid & 63;
    const int lx = lane & 15;        // pixel x (A) / filter (B)
    const int lg = lane >> 4;        // k-group

    __shared__ short in_lds[3 * 68 * IN_RS];    // 29376 B bf16, x = C-(4tx0-1)
    __shared__ float part_m[4][80];
    __shared__ float Mf[80];
    __shared__ float part_s[4][80], part_sx[4][80], part_sy[4][80];

    const float* img = in + (size_t)n * 3 * HI * WI;

    // ---- pass 1: main cols x=1..64, coalesced (16 lanes per row) ----
    {
        const int q = lane & 15;
        const int rsub = lane >> 4;               // row within group of 4
        for (int rg = w; rg < 51; rg += 4) {      // 51 groups x 4 rows = 204
            int rowid = rg * 4 + rsub;            // 0..203
            int c = (rowid >= 136) ? 2 : (rowid >= 68) ? 1 : 0;
            int r = rowid - c * 68;
            int R = 4 * ty0 - 1 + r;
            f4v v = (f4v)0.0f;
            if ((unsigned)R < HI)
                v = *(const f4v*)(img + c * HI * WI + (size_t)R * WI + 4 * tx0 + 4 * q);
            short* row = &in_lds[(c * 68 + r) * IN_RS];
            row[4 * q + 1] = f2bf(v.x);                       // b16 @ 8q+2
            *(int*)&row[4 * q + 2] = (int)pk2(v.y, v.z);      // b32 @ 8q+4
            row[4 * q + 4] = f2bf(v.w);                       // b16 @ 8q+8
        }
    }
    // ---- pass 2: margin cols x=0 and x=65..67 (1 thread per row) ----
    if (tid < 204) {
        int c = (tid >= 136) ? 2 : (tid >= 68) ? 1 : 0;
        int r = tid - c * 68;
        int R = 4 * ty0 - 1 + r;
        bool rok = (unsigned)R < HI;
        const float* src = img + c * HI * WI + (size_t)R * WI;
        float lm = (rok && tx0 > 0) ? src[4 * tx0 - 1] : 0.0f;
        f4v hv = (f4v)0.0f;
        if (rok && tx0 < 48) hv = *(const f4v*)(src + 4 * tx0 + 64);
        short* row = &in_lds[(c * 68 + r) * IN_RS];
        row[0] = f2bf(lm);
        row[65] = f2bf(hv.x);
        *(int*)&row[66] = (int)pk2(hv.y, hv.z);               // b32 @ 132
    }
    __syncthreads();

    // ---- main MFMA loop ----
    f4v acc[4][5];
#pragma unroll
    for (int a = 0; a < 4; ++a)
#pragma unroll
        for (int b = 0; b < 5; ++b) acc[a][b] = (f4v)0.0f;

#pragma unroll
    for (int c = 0; c < 3; ++c) {
#pragma unroll
        for (int kyg = 0; kyg < 2; ++kyg) {
            const int ky = kyg * 4 + lg;                     // 0..7 (7 = pad plane)
            const bfv8* wp = (const bfv8*)(wbf + ((c * 8 + ky) * 80 + lx) * 8);
            bfv8 B0 = wp[0];
            bfv8 B1 = wp[16];
            bfv8 B2 = wp[32];
            bfv8 B3 = wp[48];
            bfv8 B4 = wp[64];
            const short* ibase = &in_lds[c * (68 * IN_RS) + ky * IN_RS + 4 * lx];
#pragma unroll
            for (int mt = 0; mt < 4; ++mt) {
                bfv8 A = *(const ubfv8*)(ibase + (16 * w + 4 * mt) * IN_RS);
                acc[mt][0] = __builtin_amdgcn_mfma_f32_16x16x32_bf16(A, B0, acc[mt][0], 0, 0, 0);
                acc[mt][1] = __builtin_amdgcn_mfma_f32_16x16x32_bf16(A, B1, acc[mt][1], 0, 0, 0);
                acc[mt][2] = __builtin_amdgcn_mfma_f32_16x16x32_bf16(A, B2, acc[mt][2], 0, 0, 0);
                acc[mt][3] = __builtin_amdgcn_mfma_f32_16x16x32_bf16(A, B3, acc[mt][3], 0, 0, 0);
                acc[mt][4] = __builtin_amdgcn_mfma_f32_16x16x32_bf16(A, B4, acc[mt][4], 0, 0, 0);
            }
        }
    }

    // ---- epilogue: softmax stats. lane holds px x=(lg*4+q), filter lx+16nt ----
#pragma unroll
    for (int nt = 0; nt < 5; ++nt) {
        float m = -3.4e38f;
#pragma unroll
        for (int mt = 0; mt < 4; ++mt)
#pragma unroll
            for (int q = 0; q < 4; ++q) m = fmaxf(m, acc[mt][nt][q]);
        m = fmaxf(m, __shfl_xor(m, 16, 64));
        m = fmaxf(m, __shfl_xor(m, 32, 64));
        if (lg == 0) part_m[w][nt * 16 + lx] = m;
    }
    __syncthreads();
    if (tid < 80)
        Mf[tid] = fmaxf(fmaxf(part_m[0][tid], part_m[1][tid]),
                        fmaxf(part_m[2][tid], part_m[3][tid]));
    __syncthreads();

#pragma unroll
    for (int nt = 0; nt < 5; ++nt) {
        float M = Mf[nt * 16 + lx];
        float s = 0.0f, sx = 0.0f, sy = 0.0f;
#pragma unroll
        for (int mt = 0; mt < 4; ++mt) {
            float yv = (float)(ty0 + 4 * w + mt);
#pragma unroll
            for (int q = 0; q < 4; ++q) {
                float e = __expf(acc[mt][nt][q] - M);
                s += e;
                sx += e * (float)(tx0 + lg * 4 + q);
                sy += e * yv;
            }
        }
        s += __shfl_xor(s, 16, 64);  s += __shfl_xor(s, 32, 64);
        sx += __shfl_xor(sx, 16, 64); sx += __shfl_xor(sx, 32, 64);
        sy += __shfl_xor(sy, 16, 64); sy += __shfl_xor(sy, 32, 64);
        if (lg == 0) {
            part_s[w][nt * 16 + lx] = s;
            part_sx[w][nt * 16 + lx] = sx;
            part_sy[w][nt * 16 + lx] = sy;
        }
    }
    __syncthreads();
    if (tid < NP) {
        float S = part_s[0][tid] + part_s[1][tid] + part_s[2][tid] + part_s[3][tid];
        float SX = part_sx[0][tid] + part_sx[1][tid] + part_sx[2][tid] + part_sx[3][tid];
        float SY = part_sy[0][tid] + part_sy[1][tid] + part_sy[2][tid] + part_sy[3][tid];
        float4* o = (float4*)(stats + (((size_t)n * NP + tid) * NT + tile) * 4);
        *o = make_float4(Mf[tid], S, SX, SY);
    }
}

// ---------------------------------------------------------------------------
// Kernel 2: iterative Lucas-Kanade + per-point centroid. R12-exact (98.8us
// best): VGPR 64, 4 tasks/block, mid-body sched_barrier, S_GxT refactor.
// R13 confirmed the allocator won't go below 64 -> k_lk practical floor.
// ---------------------------------------------------------------------------
__device__ __forceinline__ float bil(const float* __restrict__ img, float x, float y) {
    float x0f = floorf(x), y0f = floorf(y);
    float wx = x - x0f, wy = y - y0f;
    int x0 = (int)x0f, y0 = (int)y0f;
    int x0i = min(max(x0, 0), WI - 1);
    int x1i = min(x0i + 1, WI - 1);
    int y0i = min(max(y0, 0), HI - 1);
    int y1i = min(y0i + 1, HI - 1);
    float v00 = img[y0i * WI + x0i];
    float v01 = img[y0i * WI + x1i];
    float v10 = img[y1i * WI + x0i];
    float v11 = img[y1i * WI + x1i];
    return v00 * (1.0f - wx) * (1.0f - wy) + v01 * wx * (1.0f - wy)
         + v10 * (1.0f - wx) * wy + v11 * wx * wy;
}

// rowoff for sample 4 (k = 256+lane), recomputed per use (saves a VGPR)
__device__ __forceinline__ int ro4_of(int lane) {
    int v = (lane < 16) ? (3841 + lane) : (4080 + lane);
    return (lane < 33) ? v : 0;
}

__device__ __forceinline__ void centroid_of(const float* __restrict__ stats,
                                            int n, int j, int lane,
                                            float& cx, float& cy) {
    const float4* st = (const float4*)(stats + (((size_t)n * NP + j) * NT) * 4);
    float4 v = st[lane & 15];
    float M = v.x, S = v.y, SX = v.z, SY = v.w;
#pragma unroll
    for (int d = 1; d < 16; d <<= 1) {
        float Mo = __shfl_xor(M, d, 64);
        float So = __shfl_xor(S, d, 64);
        float Xo = __shfl_xor(SX, d, 64);
        float Yo = __shfl_xor(SY, d, 64);
        float M2 = fmaxf(M, Mo);
        float e0 = __expf(M - M2);
        float e1 = __expf(Mo - M2);
        S = S * e0 + So * e1;
        SX = SX * e0 + Xo * e1;
        SY = SY * e0 + Yo * e1;
        M = M2;
    }
    cx = SX / S * 4.0f;     // identical in every 16-lane group -> wave-uniform
    cy = SY / S * 4.0f;
}

__device__ void lk_track(const float* __restrict__ I, const float* __restrict__ J,
                         int lane, float x, float y, float& ox_, float& oy_) {
    int rowoff[4];
    float Gx[5], Gy[5];
#pragma unroll
    for (int i = 0; i < 4; ++i) {
        int k = lane + 64 * i;
        rowoff[i] = (k / 17) * WI + k % 17;
    }

    float ixf = floorf(x), iyf = floorf(y);
    float wx = x - ixf, wy = y - iyf;
    float w00 = (1.0f - wx) * (1.0f - wy);
    float w01 = wx * (1.0f - wy);
    float w10 = (1.0f - wx) * wy;
    float w11 = wx * wy;

    float a11 = 0.0f, a12 = 0.0f, a22 = 0.0f, gxt = 0.0f, gyt = 0.0f;
    int fastI = (ixf >= 9.0f) && (ixf <= 245.0f) && (iyf >= 9.0f) && (iyf <= 245.0f);
    fastI = __builtin_amdgcn_readfirstlane(fastI);
    if (fastI) {
        int ibase = __builtin_amdgcn_readfirstlane(((int)iyf - 8) * WI + (int)ixf - 8);
        const float* Ib = I + ibase;                 // SGPR base; rowoff = voffset
#pragma unroll
        for (int i = 0; i < 5; ++i) {
            const float* p = Ib + ((i < 4) ? rowoff[i] : ro4_of(lane));
            f4v r0 = *(const uf4*)(p - 1);           // imm -4
            f4v r1 = *(const uf4*)(p + WI - 1);      // imm +1020
            f2v rm = *(const uf2*)(p - WI);          // imm -1024
            f2v r2 = *(const uf2*)(p + 2 * WI);      // imm +2048
            float t   = w00 * r0.y + w01 * r0.z + w10 * r1.y + w11 * r1.z;
            float tx1 = w00 * r0.z + w01 * r0.w + w10 * r1.z + w11 * r1.w;
            float txm = w00 * r0.x + w01 * r0.y + w10 * r1.x + w11 * r1.y;
            float typ = w00 * r1.y + w01 * r1.z + w10 * r2.x + w11 * r2.y;
            float tym = w00 * rm.x + w01 * rm.y + w10 * r0.y + w11 * r0.z;
            float gx = 0.5f * (tx1 - txm);
            float gy = 0.5f * (typ - tym);
            if (i == 4 && lane >= 33) { t = 0.0f; gx = 0.0f; gy = 0.0f; }
            Gx[i] = gx; Gy[i] = gy;
            gxt = fmaf(gx, t, gxt); gyt = fmaf(gy, t, gyt);
            a11 = fmaf(gx, gx, a11); a12 = fmaf(gx, gy, a12); a22 = fmaf(gy, gy, a22);
            if (i == 2) __builtin_amdgcn_sched_barrier(0);   // cap in-flight loads
        }
    } else {
#pragma unroll
        for (int i = 0; i < 5; ++i) {
            int k = lane + 64 * i;
            bool v_ = (k < K_LK);
            int kk = v_ ? k : 0;
            float fx = x + (float)(kk % 17 - 8);
            float fy = y + (float)(kk / 17 - 8);
            float t = bil(I, fx, fy);
            float gx = (bil(I, fx + 1.0f, fy) - bil(I, fx - 1.0f, fy)) * 0.5f;
            float gy = (bil(I, fx, fy + 1.0f) - bil(I, fx, fy - 1.0f)) * 0.5f;
            if (!v_) { t = 0.0f; gx = 0.0f; gy = 0.0f; }
            Gx[i] = gx; Gy[i] = gy;
            gxt = fmaf(gx, t, gxt); gyt = fmaf(gy, t, gyt);
            a11 = fmaf(gx, gx, a11); a12 = fmaf(gx, gy, a12); a22 = fmaf(gy, gy, a22);
            if (i == 2) __builtin_amdgcn_sched_barrier(0);
        }
    }
    a11 = rl63(wave_sum64(a11)) + 1e-6f;
    a12 = rl63(wave_sum64(a12));
    a22 = rl63(wave_sum64(a22)) + 1e-6f;
    float S_GxT = rl63(wave_sum64(gxt));
    float S_GyT = rl63(wave_sum64(gyt));
    float det = a11 * a22 - a12 * a12;
    float i11 = a22 / det, i12 = -a12 / det, i22 = a11 / det;

    float px = x, py = y;
#pragma unroll 1
    for (int s = 0; s < 10; ++s) {
        float bxv = 0.0f, byv = 0.0f;
        float jxf = floorf(px), jyf = floorf(py);
        float vx = px - jxf, vy = py - jyf;
        float u00 = (1.0f - vx) * (1.0f - vy);
        float u01 = vx * (1.0f - vy);
        float u10 = (1.0f - vx) * vy;
        float u11 = vx * vy;
        int fastJ = (jxf >= 8.0f) && (jxf <= 246.0f) && (jyf >= 8.0f) && (jyf <= 246.0f);
        fastJ = __builtin_amdgcn_readfirstlane(fastJ);
        if (fastJ) {
            int jbase = __builtin_amdgcn_readfirstlane(((int)jyf - 8) * WI + (int)jxf - 8);
            const float* Jb = J + jbase;             // SGPR base; rowoff = voffset
#pragma unroll
            for (int i = 0; i < 5; ++i) {
                const float* p = Jb + ((i < 4) ? rowoff[i] : ro4_of(lane));
                f2v q0 = *(const uf2*)(p);
                f2v q1 = *(const uf2*)(p + WI);      // imm +1024
                float v = u00 * q0.x + u01 * q0.y + u10 * q1.x + u11 * q1.y;
                bxv = fmaf(Gx[i], v, bxv);           // invalid slots: G==0 kills it
                byv = fmaf(Gy[i], v, byv);
                if (i == 2) __builtin_amdgcn_sched_barrier(0);   // cap in-flight loads
            }
        } else {
#pragma unroll
            for (int i = 0; i < 5; ++i) {
                int k = lane + 64 * i;
                int kk = (k < K_LK) ? k : 0;
                float v = bil(J, px + (float)(kk % 17 - 8), py + (float)(kk / 17 - 8));
                bxv = fmaf(Gx[i], v, bxv);
                byv = fmaf(Gy[i], v, byv);
                if (i == 2) __builtin_amdgcn_sched_barrier(0);
            }
        }
        float bxs = S_GxT - rl63(wave_sum64(bxv));
        float bys = S_GyT - rl63(wave_sum64(byv));
        px = fmaf(i11, bxs, fmaf(i12, bys, px));
        py = fmaf(i12, bxs, fmaf(i22, bys, py));
    }
    ox_ = px;
    oy_ = py;
}

__global__ __launch_bounds__(256) void k_lk(const float* __restrict__ gray,
                                            const float* __restrict__ stats,
                                            float* __restrict__ locs,
                                            float* __restrict__ out_next,
                                            float* __restrict__ out_fb,
                                            float* __restrict__ out_back) {
    int wid = blockIdx.x * 4 + (threadIdx.x >> 6);   // 4 independent tasks/block
    int lane = threadIdx.x & 63;
    int variant = wid / (NPAIR * NP);
    int r = wid - variant * (NPAIR * NP);
    int pr = r / NP;
    int j = r - pr * NP;
    int b = pr / 15;
    int t = pr - b * 15;
    int n0 = b * 16 + t;
    const float* I = gray + (size_t)n0 * HI * WI;
    const float* J = gray + (size_t)(n0 + 1) * HI * WI;
    int o = (pr * NP + j) * 2;
    if (variant == 0) {
        float x, y;
        centroid_of(stats, n0, j, lane, x, y);
        if (lane == 0) { locs[(n0 * NP + j) * 2] = x; locs[(n0 * NP + j) * 2 + 1] = y; }
        float nx, ny;
        lk_track(I, J, lane, x, y, nx, ny);
        if (lane == 0) { out_next[o] = nx; out_next[o + 1] = ny; }
        float fx, fy;
        lk_track(J, I, lane, nx, ny, fx, fy);
        if (lane == 0) { out_fb[o] = fx; out_fb[o + 1] = fy; }
    } else {
        float x, y;
        centroid_of(stats, n0 + 1, j, lane, x, y);
        if (lane == 0) {
            locs[((n0 + 1) * NP + j) * 2] = x;
            locs[((n0 + 1) * NP + j) * 2 + 1] = y;
        }
        float bx, by;
        lk_track(J, I, lane, x, y, bx, by);
        if (lane == 0) { out_back[o] = bx; out_back[o + 1] = by; }
    }
}

// ---------------------------------------------------------------------------
extern "C" void kernel_launch(void* const* d_in, const int* in_sizes, int n_in,
                              void* d_out, int out_size, void* d_ws, size_t ws_size,
                              hipStream_t stream) {
    const float* inputs = (const float*)d_in[0];
    const float* det_w  = (const float*)d_in[1];
    // det_b (d_in[2]) is softmax-shift-invariant -> unused
    float* out = (float*)d_out;

    float* gray  = (float*)d_ws;                                       // 32 MiB
    float* stats = (float*)((char*)d_ws + (size_t)NIMG * HI * WI * 4); // 2.2 MiB
    short* wbf   = (short*)((char*)d_ws + (size_t)NIMG * HI * WI * 4
                            + (size_t)NIMG * NP * NT * 4 * 4);         // 30 KiB

    float* locs   = out;                    // [8,16,68,2]
    float* next_p = out + 17408;
    float* fb_p   = out + 33728;
    float* back_p = out + 50048;

    hipLaunchKernelGGL(k_wprep, dim3(16), dim3(256), 0, stream, det_w, wbf);
    hipLaunchKernelGGL(k_convgray, dim3(NCONVB + NGRAYB), dim3(256), 0, stream,
                       inputs, wbf, stats, gray);
    hipLaunchKernelGGL(k_lk, dim3(NTASK / 4), dim3(256), 0, stream,
                       gray, stats, locs, next_p, fb_p, back_p);
}

// Round 15
// 120.501 us; speedup vs baseline: 1.3376x; 1.2862x over previous
//
#include <hip/hip_runtime.h>
#include <math.h>

#define HI 256
#define WI 256
#define NIMG 128          // B*S
#define NP 68             // landmarks
#define NT 16             // 4x4 tiles of 16x16 outputs per 64x64 heatmap
#define NPAIR 120         // B*(S-1)
#define K_LK 289          // 17x17 window
#define NCONVB (NT * NIMG)   // 2048 conv blocks (gray fused in)
#define NTASK (2 * NPAIR * NP)   // 16320 LK tasks
#define PSTR 28           // LK LDS patch row stride (floats); 112B = 16B-aligned rows

typedef float f4v __attribute__((ext_vector_type(4)));
typedef float f2v __attribute__((ext_vector_type(2)));
typedef f4v __attribute__((aligned(4))) uf4;
typedef f2v __attribute__((aligned(4))) uf2;

typedef short bfv8 __attribute__((ext_vector_type(8)));   // 8 bf16 (MFMA frag)
typedef bfv8 __attribute__((aligned(8))) ubfv8;           // 8B-aligned LDS view

#define WBF_ELEMS (3 * 8 * 80 * 8)   // bf16 weight image [c][ky0..7][f0..79][kx0..7]

__device__ __forceinline__ short f2bf(float x) {
    unsigned u = __builtin_bit_cast(unsigned, x);
    u += 0x7fffu + ((u >> 16) & 1u);          // round-to-nearest-even
    return (short)(u >> 16);
}
__device__ __forceinline__ unsigned pk2(float lo, float hi) {
    return (unsigned)(unsigned short)f2bf(lo) | ((unsigned)(unsigned short)f2bf(hi) << 16);
}

// ---- DPP wave-64 sum; lane 63 holds the total (6 VALU ops, no LDS round-trip)
#define DPPA(ctrl, rm)                                                          \
    {                                                                           \
        int m_ = __builtin_amdgcn_update_dpp(0, __builtin_bit_cast(int, x),     \
                                             ctrl, rm, 0xf, true);              \
        x += __builtin_bit_cast(float, m_);                                     \
    }
__device__ __forceinline__ float wave_sum64(float x) {
    DPPA(0x111, 0xf)   // row_shr:1
    DPPA(0x112, 0xf)   // row_shr:2
    DPPA(0x114, 0xf)   // row_shr:4
    DPPA(0x118, 0xf)   // row_shr:8
    DPPA(0x142, 0xa)   // row_bcast:15 -> rows 1,3
    DPPA(0x143, 0xc)   // row_bcast:31 -> rows 2,3
    return x;          // lane 63 = total
}
__device__ __forceinline__ float rl63(float x) {
    return __builtin_bit_cast(float,
        __builtin_amdgcn_readlane(__builtin_bit_cast(int, x), 63));
}

// ---------------------------------------------------------------------------
// Kernel 0: weight prep -> bf16 [c][ky(8)][p(80)][kx(8)], pads zero. Grid 16.
// ---------------------------------------------------------------------------
__global__ __launch_bounds__(256) void k_wprep(const float* __restrict__ dw,
                                               short* __restrict__ wbf) {
    for (int ii = blockIdx.x * 256 + threadIdx.x; ii < WBF_ELEMS / 2;
         ii += 16 * 256) {
        int s0 = 2 * ii;                 // short index, kx = s0 & 7 (even)
        int kx = s0 & 7;
        int rest = s0 >> 3;              // (c*8+ky)*80 + p
        int p = rest % 80;
        int cky = rest / 80;             // c*8+ky
        int c = cky >> 3;
        int ky = cky & 7;
        unsigned lo = 0, hi = 0;
        if (ky < 7 && p < NP) {
            const float* wp = dw + p * 147 + (c * 7 + ky) * 7;
            lo = (unsigned short)f2bf(wp[kx]);
            if (kx + 1 < 7) hi = (unsigned short)f2bf(wp[kx + 1]);
        }
        ((int*)wbf)[ii] = (int)(lo | (hi << 16));
    }
}

// ---------------------------------------------------------------------------
// Kernel 1: conv 7x7/s4 MFMA + softmax stats, WITH gray fused into staging.
// R15: pass 1 loads all 3 channels of each patch row (256B-coalesced per
// channel), writes bf16 LDS rows AND the f32 gray core tile (rows r=1..64 =
// image rows 4ty0..4ty0+63, cols 4tx0..4tx0+63; 16 disjoint tiles cover the
// image exactly once; math (a+b+c)*(1/3) identical to the old k_gray).
// Deletes the separate 1024 gray blocks and their 100MB input re-read.
// ---------------------------------------------------------------------------
#define IN_RS 72                     // LDS input row stride (shorts), 144B
__global__ __launch_bounds__(256, 3) void k_convgray(const float* __restrict__ in,
                                                     const short* __restrict__ wbf,
                                                     float* __restrict__ stats,
                                                     float* __restrict__ gray) {
    const int bid = blockIdx.x;
    const int tile = bid & 15;
    const int n = bid >> 4;
    const int ty0 = (tile >> 2) * 16;
    const int tx0 = (tile & 3) * 16;
    const int tid = threadIdx.x;
    const int w = __builtin_amdgcn_readfirstlane(tid >> 6);   // wave: rows 4w..4w+3
    const int lane = tid & 63;
    const int lx = lane & 15;        // pixel x (A) / filter (B)
    const int lg = lane >> 4;        // k-group

    __shared__ short in_lds[3 * 68 * IN_RS];    // 29376 B bf16, x = C-(4tx0-1)
    __shared__ float part_m[4][80];
    __shared__ float Mf[80];
    __shared__ float part_s[4][80], part_sx[4][80], part_sy[4][80];

    const float* img = in + (size_t)n * 3 * HI * WI;
    const float kk = 1.0f / 3.0f;

    // ---- pass 1: main cols x=1..64, 3 channels/row, + gray core write ----
    {
        const int q = lane & 15;
        const int rsub = lane >> 4;
#pragma unroll
        for (int rr = 0; rr < 5; ++rr) {
            int r = rr * 16 + w * 4 + rsub;       // 0..79
            if (r < 68) {
                int R = 4 * ty0 - 1 + r;
                f4v v0 = (f4v)0.0f, v1 = (f4v)0.0f, v2 = (f4v)0.0f;
                if ((unsigned)R < HI) {
                    const float* s = img + (size_t)R * WI + 4 * tx0 + 4 * q;
                    v0 = *(const f4v*)(s);
                    v1 = *(const f4v*)(s + HI * WI);
                    v2 = *(const f4v*)(s + 2 * HI * WI);
                }
                short* r0 = &in_lds[r * IN_RS];
                r0[4 * q + 1] = f2bf(v0.x);
                *(int*)&r0[4 * q + 2] = (int)pk2(v0.y, v0.z);
                r0[4 * q + 4] = f2bf(v0.w);
                short* r1 = &in_lds[(68 + r) * IN_RS];
                r1[4 * q + 1] = f2bf(v1.x);
                *(int*)&r1[4 * q + 2] = (int)pk2(v1.y, v1.z);
                r1[4 * q + 4] = f2bf(v1.w);
                short* r2 = &in_lds[(136 + r) * IN_RS];
                r2[4 * q + 1] = f2bf(v2.x);
                *(int*)&r2[4 * q + 2] = (int)pk2(v2.y, v2.z);
                r2[4 * q + 4] = f2bf(v2.w);
                if (r >= 1 && r <= 64) {
                    f4v g = (v0 + v1 + v2) * kk;
                    *(f4v*)&gray[(size_t)n * HI * WI + (size_t)R * WI + 4 * tx0 + 4 * q] = g;
                }
            }
        }
    }
    // ---- pass 2: margin cols x=0 and x=65..67 (1 thread per row) ----
    if (tid < 204) {
        int c = (tid >= 136) ? 2 : (tid >= 68) ? 1 : 0;
        int r = tid - c * 68;
        int R = 4 * ty0 - 1 + r;
        bool rok = (unsigned)R < HI;
        const float* src = img + c * HI * WI + (size_t)R * WI;
        float lm = (rok && tx0 > 0) ? src[4 * tx0 - 1] : 0.0f;
        f4v hv = (f4v)0.0f;
        if (rok && tx0 < 48) hv = *(const f4v*)(src + 4 * tx0 + 64);
        short* row = &in_lds[(c * 68 + r) * IN_RS];
        row[0] = f2bf(lm);
        row[65] = f2bf(hv.x);
        *(int*)&row[66] = (int)pk2(hv.y, hv.z);
    }
    __syncthreads();

    // ---- main MFMA loop ----
    f4v acc[4][5];
#pragma unroll
    for (int a = 0; a < 4; ++a)
#pragma unroll
        for (int b = 0; b < 5; ++b) acc[a][b] = (f4v)0.0f;

#pragma unroll
    for (int c = 0; c < 3; ++c) {
#pragma unroll
        for (int kyg = 0; kyg < 2; ++kyg) {
            const int ky = kyg * 4 + lg;                     // 0..7 (7 = pad plane)
            const bfv8* wp = (const bfv8*)(wbf + ((c * 8 + ky) * 80 + lx) * 8);
            bfv8 B0 = wp[0];
            bfv8 B1 = wp[16];
            bfv8 B2 = wp[32];
            bfv8 B3 = wp[48];
            bfv8 B4 = wp[64];
            const short* ibase = &in_lds[c * (68 * IN_RS) + ky * IN_RS + 4 * lx];
#pragma unroll
            for (int mt = 0; mt < 4; ++mt) {
                bfv8 A = *(const ubfv8*)(ibase + (16 * w + 4 * mt) * IN_RS);
                acc[mt][0] = __builtin_amdgcn_mfma_f32_16x16x32_bf16(A, B0, acc[mt][0], 0, 0, 0);
                acc[mt][1] = __builtin_amdgcn_mfma_f32_16x16x32_bf16(A, B1, acc[mt][1], 0, 0, 0);
                acc[mt][2] = __builtin_amdgcn_mfma_f32_16x16x32_bf16(A, B2, acc[mt][2], 0, 0, 0);
                acc[mt][3] = __builtin_amdgcn_mfma_f32_16x16x32_bf16(A, B3, acc[mt][3], 0, 0, 0);
                acc[mt][4] = __builtin_amdgcn_mfma_f32_16x16x32_bf16(A, B4, acc[mt][4], 0, 0, 0);
            }
        }
    }

    // ---- epilogue: softmax stats. lane holds px x=(lg*4+q), filter lx+16nt ----
#pragma unroll
    for (int nt = 0; nt < 5; ++nt) {
        float m = -3.4e38f;
#pragma unroll
        for (int mt = 0; mt < 4; ++mt)
#pragma unroll
            for (int q = 0; q < 4; ++q) m = fmaxf(m, acc[mt][nt][q]);
        m = fmaxf(m, __shfl_xor(m, 16, 64));
        m = fmaxf(m, __shfl_xor(m, 32, 64));
        if (lg == 0) part_m[w][nt * 16 + lx] = m;
    }
    __syncthreads();
    if (tid < 80)
        Mf[tid] = fmaxf(fmaxf(part_m[0][tid], part_m[1][tid]),
                        fmaxf(part_m[2][tid], part_m[3][tid]));
    __syncthreads();

#pragma unroll
    for (int nt = 0; nt < 5; ++nt) {
        float M = Mf[nt * 16 + lx];
        float s = 0.0f, sx = 0.0f, sy = 0.0f;
#pragma unroll
        for (int mt = 0; mt < 4; ++mt) {
            float yv = (float)(ty0 + 4 * w + mt);
#pragma unroll
            for (int q = 0; q < 4; ++q) {
                float e = __expf(acc[mt][nt][q] - M);
                s += e;
                sx += e * (float)(tx0 + lg * 4 + q);
                sy += e * yv;
            }
        }
        s += __shfl_xor(s, 16, 64);  s += __shfl_xor(s, 32, 64);
        sx += __shfl_xor(sx, 16, 64); sx += __shfl_xor(sx, 32, 64);
        sy += __shfl_xor(sy, 16, 64); sy += __shfl_xor(sy, 32, 64);
        if (lg == 0) {
            part_s[w][nt * 16 + lx] = s;
            part_sx[w][nt * 16 + lx] = sx;
            part_sy[w][nt * 16 + lx] = sy;
        }
    }
    __syncthreads();
    if (tid < NP) {
        float S = part_s[0][tid] + part_s[1][tid] + part_s[2][tid] + part_s[3][tid];
        float SX = part_sx[0][tid] + part_sx[1][tid] + part_sx[2][tid] + part_sx[3][tid];
        float SY = part_sy[0][tid] + part_sy[1][tid] + part_sy[2][tid] + part_sy[3][tid];
        float4* o = (float4*)(stats + (((size_t)n * NP + tid) * NT + tile) * 4);
        *o = make_float4(Mf[tid], S, SX, SY);
    }
}

// ---------------------------------------------------------------------------
// Kernel 2: Lucas-Kanade + centroid. R15: LDS-staged patches.
// R10-R14 evidence: occupancy 30->40% with dur flat => k_lk is bound by the
// CU-SHARED L1 (16 waves x 2-3KB scattered patches thrash 32KB L1; ~500
// line-touches/track ~ the observed 99us). Fix: stage the patch in LDS
// (per-wave 24x28 f32 buffer): I 20x20 for setup, then SAME buffer restaged
// with J 24x24 for the GN steps while floor(p) stays within +-3 of start
// (wave-uniform check; else exact global/bil fallback). All values are f32
// COPIES -> bit-identical math. VGPR may rise to ~80: free, 64..128 is the
// same 4-wave tier (R10 vs R12).
// ---------------------------------------------------------------------------
__device__ __forceinline__ float bil(const float* __restrict__ img, float x, float y) {
    float x0f = floorf(x), y0f = floorf(y);
    float wx = x - x0f, wy = y - y0f;
    int x0 = (int)x0f, y0 = (int)y0f;
    int x0i = min(max(x0, 0), WI - 1);
    int x1i = min(x0i + 1, WI - 1);
    int y0i = min(max(y0, 0), HI - 1);
    int y1i = min(y0i + 1, HI - 1);
    float v00 = img[y0i * WI + x0i];
    float v01 = img[y0i * WI + x1i];
    float v10 = img[y1i * WI + x0i];
    float v11 = img[y1i * WI + x1i];
    return v00 * (1.0f - wx) * (1.0f - wy) + v01 * wx * (1.0f - wy)
         + v10 * (1.0f - wx) * wy + v11 * wx * wy;
}

__device__ __forceinline__ void centroid_of(const float* __restrict__ stats,
                                            int n, int j, int lane,
                                            float& cx, float& cy) {
    const float4* st = (const float4*)(stats + (((size_t)n * NP + j) * NT) * 4);
    float4 v = st[lane & 15];
    float M = v.x, S = v.y, SX = v.z, SY = v.w;
#pragma unroll
    for (int d = 1; d < 16; d <<= 1) {
        float Mo = __shfl_xor(M, d, 64);
        float So = __shfl_xor(S, d, 64);
        float Xo = __shfl_xor(SX, d, 64);
        float Yo = __shfl_xor(SY, d, 64);
        float M2 = fmaxf(M, Mo);
        float e0 = __expf(M - M2);
        float e1 = __expf(Mo - M2);
        S = S * e0 + So * e1;
        SX = SX * e0 + Xo * e1;
        SY = SY * e0 + Yo * e1;
        M = M2;
    }
    cx = SX / S * 4.0f;
    cy = SY / S * 4.0f;
}

__device__ void lk_track(float* __restrict__ P,
                         const float* __restrict__ I, const float* __restrict__ J,
                         int lane, float x, float y, float& ox_, float& oy_) {
    int rowoff[5], loff[5];
    float Gx[5], Gy[5];
#pragma unroll
    for (int i = 0; i < 5; ++i) {
        int k = lane + 64 * i;
        int kk = (k < K_LK) ? k : 0;
        int dy = kk / 17, dx = kk % 17;
        rowoff[i] = dy * WI + dx;
        loff[i] = dy * PSTR + dx;
    }

    float ixf = floorf(x), iyf = floorf(y);
    int icx = (int)ixf, icy = (int)iyf;
    float wx = x - ixf, wy = y - iyf;
    float w00 = (1.0f - wx) * (1.0f - wy);
    float w01 = wx * (1.0f - wy);
    float w10 = (1.0f - wx) * wy;
    float w11 = wx * wy;

    int canJ = (icx >= 11) && (icx <= 243) && (icy >= 11) && (icy <= 243);
    canJ = __builtin_amdgcn_readfirstlane(canJ);

    float a11 = 0.0f, a12 = 0.0f, a22 = 0.0f, gxt = 0.0f, gyt = 0.0f;
    if (canJ) {
        // ---- stage I 20x20 at (icx-9, icy-9), stride PSTR ----
        {
            const float* src = I + (icy - 9) * WI + (icx - 9);
#pragma unroll
            for (int p = 0; p < 2; ++p) {
                int idx = lane + 64 * p;
                if (idx < 100) {
                    int row = idx / 5, cq = idx - row * 5;
                    *(f4v*)&P[row * PSTR + 4 * cq] = *(const uf4*)(src + row * WI + 4 * cq);
                }
            }
        }
        asm volatile("s_waitcnt lgkmcnt(0) vmcnt(0)" ::: "memory");
        // setup from LDS: sample (dy,dx) local base = 29 + loff (origin icx-9)
#pragma unroll
        for (int i = 0; i < 5; ++i) {
            const float* pb = P + 29 + loff[i];
            float r0x = pb[-1], r0y = pb[0], r0z = pb[1], r0w = pb[2];
            float r1x = pb[PSTR - 1], r1y = pb[PSTR], r1z = pb[PSTR + 1], r1w = pb[PSTR + 2];
            float rmx = pb[-PSTR], rmy = pb[-PSTR + 1];
            float r2x = pb[2 * PSTR], r2y = pb[2 * PSTR + 1];
            float t   = w00 * r0y + w01 * r0z + w10 * r1y + w11 * r1z;
            float tx1 = w00 * r0z + w01 * r0w + w10 * r1z + w11 * r1w;
            float txm = w00 * r0x + w01 * r0y + w10 * r1x + w11 * r1y;
            float typ = w00 * r1y + w01 * r1z + w10 * r2x + w11 * r2y;
            float tym = w00 * rmx + w01 * rmy + w10 * r0y + w11 * r0z;
            float gx = 0.5f * (tx1 - txm);
            float gy = 0.5f * (typ - tym);
            if (i == 4 && lane >= 33) { t = 0.0f; gx = 0.0f; gy = 0.0f; }
            Gx[i] = gx; Gy[i] = gy;
            gxt = fmaf(gx, t, gxt); gyt = fmaf(gy, t, gyt);
            a11 = fmaf(gx, gx, a11); a12 = fmaf(gx, gy, a12); a22 = fmaf(gy, gy, a22);
        }
        // ---- restage with J 24x24 at (icx-11, icy-11) ----
        asm volatile("s_waitcnt lgkmcnt(0)" ::: "memory");
        {
            const float* srj = J + (icy - 11) * WI + (icx - 11);
#pragma unroll
            for (int p = 0; p < 3; ++p) {
                int idx = lane + 64 * p;
                if (idx < 144) {
                    int row = idx / 6, cq = idx - row * 6;
                    *(f4v*)&P[row * PSTR + 4 * cq] = *(const uf4*)(srj + row * WI + 4 * cq);
                }
            }
        }
        asm volatile("s_waitcnt lgkmcnt(0) vmcnt(0)" ::: "memory");
    } else {
        // ---- exact bil fallback setup (boundary tracks) ----
#pragma unroll
        for (int i = 0; i < 5; ++i) {
            int k = lane + 64 * i;
            bool v_ = (k < K_LK);
            int kk = v_ ? k : 0;
            float fx = x + (float)(kk % 17 - 8);
            float fy = y + (float)(kk / 17 - 8);
            float t = bil(I, fx, fy);
            float gx = (bil(I, fx + 1.0f, fy) - bil(I, fx - 1.0f, fy)) * 0.5f;
            float gy = (bil(I, fx, fy + 1.0f) - bil(I, fx, fy - 1.0f)) * 0.5f;
            if (!v_) { t = 0.0f; gx = 0.0f; gy = 0.0f; }
            Gx[i] = gx; Gy[i] = gy;
            gxt = fmaf(gx, t, gxt); gyt = fmaf(gy, t, gyt);
            a11 = fmaf(gx, gx, a11); a12 = fmaf(gx, gy, a12); a22 = fmaf(gy, gy, a22);
        }
    }
    a11 = rl63(wave_sum64(a11)) + 1e-6f;
    a12 = rl63(wave_sum64(a12));
    a22 = rl63(wave_sum64(a22)) + 1e-6f;
    float S_GxT = rl63(wave_sum64(gxt));
    float S_GyT = rl63(wave_sum64(gyt));
    float det = a11 * a22 - a12 * a12;
    float i11 = a22 / det, i12 = -a12 / det, i22 = a11 / det;

    float px = x, py = y;
#pragma unroll 1
    for (int s = 0; s < 10; ++s) {
        float bxv = 0.0f, byv = 0.0f;
        float jxf = floorf(px), jyf = floorf(py);
        float vx = px - jxf, vy = py - jyf;
        float u00 = (1.0f - vx) * (1.0f - vy);
        float u01 = vx * (1.0f - vy);
        float u10 = (1.0f - vx) * vy;
        float u11 = vx * vy;
        int jx = (int)jxf, jy = (int)jyf;
        int inWin = canJ && ((unsigned)(jx - icx + 3) <= 6u)
                         && ((unsigned)(jy - icy + 3) <= 6u);
        inWin = __builtin_amdgcn_readfirstlane(inWin);
        if (inWin) {
            int sb = (jy - icy + 3) * PSTR + (jx - icx + 3);
#pragma unroll
            for (int i = 0; i < 5; ++i) {
                const float* pb = P + sb + loff[i];
                float v = u00 * pb[0] + u01 * pb[1] + u10 * pb[PSTR] + u11 * pb[PSTR + 1];
                bxv = fmaf(Gx[i], v, bxv);           // invalid slots: G==0 kills it
                byv = fmaf(Gy[i], v, byv);
            }
        } else {
            int fastJ = (jxf >= 8.0f) && (jxf <= 246.0f) && (jyf >= 8.0f) && (jyf <= 246.0f);
            fastJ = __builtin_amdgcn_readfirstlane(fastJ);
            if (fastJ) {
                int jbase = __builtin_amdgcn_readfirstlane((jy - 8) * WI + jx - 8);
                const float* Jb = J + jbase;
#pragma unroll
                for (int i = 0; i < 5; ++i) {
                    const float* p = Jb + rowoff[i];
                    f2v q0 = *(const uf2*)(p);
                    f2v q1 = *(const uf2*)(p + WI);
                    float v = u00 * q0.x + u01 * q0.y + u10 * q1.x + u11 * q1.y;
                    bxv = fmaf(Gx[i], v, bxv);
                    byv = fmaf(Gy[i], v, byv);
                }
            } else {
#pragma unroll
                for (int i = 0; i < 5; ++i) {
                    int k = lane + 64 * i;
                    int kk = (k < K_LK) ? k : 0;
                    float v = bil(J, px + (float)(kk % 17 - 8), py + (float)(kk / 17 - 8));
                    bxv = fmaf(Gx[i], v, bxv);
                    byv = fmaf(Gy[i], v, byv);
                }
            }
        }
        float bxs = S_GxT - rl63(wave_sum64(bxv));
        float bys = S_GyT - rl63(wave_sum64(byv));
        px = fmaf(i11, bxs, fmaf(i12, bys, px));
        py = fmaf(i12, bxs, fmaf(i22, bys, py));
    }
    ox_ = px;
    oy_ = py;
}

__global__ __launch_bounds__(256) void k_lk(const float* __restrict__ gray,
                                            const float* __restrict__ stats,
                                            float* __restrict__ locs,
                                            float* __restrict__ out_next,
                                            float* __restrict__ out_fb,
                                            float* __restrict__ out_back) {
    __shared__ float patch[4][24 * PSTR];            // 10752 B: per-wave 24x28 f32
    float* P = patch[threadIdx.x >> 6];
    int wid = blockIdx.x * 4 + (threadIdx.x >> 6);   // 4 independent tasks/block
    int lane = threadIdx.x & 63;
    int variant = wid / (NPAIR * NP);
    int r = wid - variant * (NPAIR * NP);
    int pr = r / NP;
    int j = r - pr * NP;
    int b = pr / 15;
    int t = pr - b * 15;
    int n0 = b * 16 + t;
    const float* I = gray + (size_t)n0 * HI * WI;
    const float* J = gray + (size_t)(n0 + 1) * HI * WI;
    int o = (pr * NP + j) * 2;
    if (variant == 0) {
        float x, y;
        centroid_of(stats, n0, j, lane, x, y);
        if (lane == 0) { locs[(n0 * NP + j) * 2] = x; locs[(n0 * NP + j) * 2 + 1] = y; }
        float nx, ny;
        lk_track(P, I, J, lane, x, y, nx, ny);
        if (lane == 0) { out_next[o] = nx; out_next[o + 1] = ny; }
        float fx, fy;
        lk_track(P, J, I, lane, nx, ny, fx, fy);
        if (lane == 0) { out_fb[o] = fx; out_fb[o + 1] = fy; }
    } else {
        float x, y;
        centroid_of(stats, n0 + 1, j, lane, x, y);
        if (lane == 0) {
            locs[((n0 + 1) * NP + j) * 2] = x;
            locs[((n0 + 1) * NP + j) * 2 + 1] = y;
        }
        float bx, by;
        lk_track(P, J, I, lane, x, y, bx, by);
        if (lane == 0) { out_back[o] = bx; out_back[o + 1] = by; }
    }
}

// ---------------------------------------------------------------------------
extern "C" void kernel_launch(void* const* d_in, const int* in_sizes, int n_in,
                              void* d_out, int out_size, void* d_ws, size_t ws_size,
                              hipStream_t stream) {
    const float* inputs = (const float*)d_in[0];
    const float* det_w  = (const float*)d_in[1];
    // det_b (d_in[2]) is softmax-shift-invariant -> unused
    float* out = (float*)d_out;

    float* gray  = (float*)d_ws;                                       // 32 MiB
    float* stats = (float*)((char*)d_ws + (size_t)NIMG * HI * WI * 4); // 2.2 MiB
    short* wbf   = (short*)((char*)d_ws + (size_t)NIMG * HI * WI * 4
                            + (size_t)NIMG * NP * NT * 4 * 4);         // 30 KiB

    float* locs   = out;                    // [8,16,68,2]
    float* next_p = out + 17408;
    float* fb_p   = out + 33728;
    float* back_p = out + 50048;

    hipLaunchKernelGGL(k_wprep, dim3(16), dim3(256), 0, stream, det_w, wbf);
    hipLaunchKernelGGL(k_convgray, dim3(NCONVB), dim3(256), 0, stream,
                       inputs, wbf, stats, gray);
    hipLaunchKernelGGL(k_lk, dim3(NTASK / 4), dim3(256), 0, stream,
                       gray, stats, locs, next_p, fb_p, back_p);
}